// Round 7
// baseline (473.951 us; speedup 1.0000x reference)
//
#include <hip/hip_runtime.h>
#include <hip/hip_bf16.h>
#include <stdint.h>

typedef __attribute__((ext_vector_type(8))) short bf16x8;   // 8 bf16 = 4 VGPRs
typedef __attribute__((ext_vector_type(4))) float f32x4;

#define LOG2E 1.4426950408889634f

__device__ __forceinline__ float exp2_fast(float x) {
  float r; asm("v_exp_f32 %0, %1" : "=v"(r) : "v"(x)); return r;
}

__device__ __forceinline__ float bf16bits_to_f32(unsigned short h) {
  union { uint32_t u; float f; } c;
  c.u = ((uint32_t)h) << 16;
  return c.f;
}

// ---------------- async global -> LDS (16B per lane) ----------------
__device__ __forceinline__ void gload_lds16(const void* g, void* l) {
  typedef __attribute__((address_space(1))) void gv_t;
  typedef __attribute__((address_space(3))) void lv_t;
  __builtin_amdgcn_global_load_lds((gv_t*)(uintptr_t)g,
                                   (lv_t*)(uint32_t)(uintptr_t)l, 16, 0, 0);
}

// ---------------- fp32 -> bf16 cast ----------------
__global__ __launch_bounds__(256) void cvt_bf16(const float* __restrict__ src,
                                                __hip_bfloat16* __restrict__ dst, int n4) {
  int i = blockIdx.x * 256 + threadIdx.x;
  if (i < n4) {
    float4 f = ((const float4*)src)[i];
    union { ushort4 u; __hip_bfloat16 h[4]; } pk;
    pk.h[0] = __float2bfloat16(f.x);
    pk.h[1] = __float2bfloat16(f.y);
    pk.h[2] = __float2bfloat16(f.z);
    pk.h[3] = __float2bfloat16(f.w);
    ((ushort4*)dst)[i] = pk.u;
  }
}

// fp32 -> bf16 with scale + zero-padding beyond n4src (63-row rel tables -> 64 rows)
__global__ __launch_bounds__(256) void cvt_bf16_pad(const float* __restrict__ src,
                                                    __hip_bfloat16* __restrict__ dst,
                                                    int n4src, int n4tot, float scale) {
  int i = blockIdx.x * 256 + threadIdx.x;
  if (i < n4tot) {
    float4 f = (i < n4src) ? ((const float4*)src)[i] : make_float4(0.f, 0.f, 0.f, 0.f);
    union { ushort4 u; __hip_bfloat16 h[4]; } pk;
    pk.h[0] = __float2bfloat16(f.x * scale);
    pk.h[1] = __float2bfloat16(f.y * scale);
    pk.h[2] = __float2bfloat16(f.z * scale);
    pk.h[3] = __float2bfloat16(f.w * scale);
    ((ushort4*)dst)[i] = pk.u;
  }
}

// ---------------- shared 128x128 bf16 GEMM body (A[M][K] @ B[N][K]^T) ----------------
__device__ __forceinline__ void gemm_tile_compute(const __hip_bfloat16* __restrict__ A,
                                                  const __hip_bfloat16* __restrict__ Bm,
                                                  int K, int bm, int bn,
                                                  f32x4 acc[4][4], char* lbase) {
  const int tid = threadIdx.x;
  const int lane = tid & 63, w = tid >> 6;
  const int wr = w >> 1, wc = w & 1;
  const int rrow = lane & 15, g16 = lane >> 4;

  for (int k0 = 0; k0 < K; k0 += 32) {
    #pragma unroll
    for (int i = 0; i < 2; ++i) {
      int c = i * 4 + w;
      int b = c * 1024 + (lane << 4);
      int row = b >> 6;           // 64B rows
      int cbs = ((b >> 4) & 3) ^ (row & 3);
      const char* ga = (const char*)(A + (size_t)(bm * 128 + row) * K + k0) + cbs * 16;
      gload_lds16(ga, lbase + c * 1024);
      const char* gb = (const char*)(Bm + (size_t)(bn * 128 + row) * K + k0) + cbs * 16;
      gload_lds16(gb, lbase + 8192 + c * 1024);
    }
    asm volatile("s_waitcnt vmcnt(0)" ::: "memory");
    __syncthreads();

    bf16x8 af[4], bfr[4];
    #pragma unroll
    for (int i = 0; i < 4; ++i) {
      int row = wr * 64 + i * 16 + rrow;
      af[i] = *(const bf16x8*)(lbase + row * 64 + ((g16 * 16) ^ ((row & 3) << 4)));
      int col = wc * 64 + i * 16 + rrow;
      bfr[i] = *(const bf16x8*)(lbase + 8192 + col * 64 + ((g16 * 16) ^ ((col & 3) << 4)));
    }
    __builtin_amdgcn_s_setprio(1);
    #pragma unroll
    for (int i = 0; i < 4; ++i)
      #pragma unroll
      for (int j = 0; j < 4; ++j)
        acc[i][j] = __builtin_amdgcn_mfma_f32_16x16x32_bf16(af[i], bfr[j], acc[i][j], 0, 0, 0);
    __builtin_amdgcn_s_setprio(0);
    __syncthreads();
  }
}

// ---------------- qkv GEMM: x(8192x768) @ qkv_w(2304x768)^T + b -> packed Q/K/V + prekv ----
__global__ __launch_bounds__(256) void gemm_qkv_kernel(
    const __hip_bfloat16* __restrict__ xb, const __hip_bfloat16* __restrict__ wqkv,
    const float* __restrict__ qkv_b,
    __hip_bfloat16* __restrict__ Qws, __hip_bfloat16* __restrict__ Kws,
    __hip_bfloat16* __restrict__ Vws, float* __restrict__ prekv) {
  __shared__ char smem[16384];
  f32x4 acc[4][4];
  const f32x4 z4 = {0.f, 0.f, 0.f, 0.f};
  #pragma unroll
  for (int i = 0; i < 4; ++i)
    #pragma unroll
    for (int j = 0; j < 4; ++j) acc[i][j] = z4;

  const int bn = blockIdx.x, bm = blockIdx.y;
  gemm_tile_compute(xb, wqkv, 768, bm, bn, acc, smem);

  const int lane = threadIdx.x & 63, w = threadIdx.x >> 6;
  const int wr = w >> 1, wc = w & 1;
  const int col0 = lane & 15, g = lane >> 4;
  #pragma unroll
  for (int j = 0; j < 4; ++j) {
    int n = bn * 128 + wc * 64 + j * 16 + col0;
    float bias = qkv_b[n];
    int which = n / 768;
    int head = (n >> 6) % 12;
    int d = n & 63;
    #pragma unroll
    for (int i = 0; i < 4; ++i) {
      #pragma unroll
      for (int r = 0; r < 4; ++r) {
        int m = bm * 128 + wr * 64 + i * 16 + g * 4 + r;
        float v = acc[i][j][r] + bias;
        int b = m >> 10, t = m & 1023;
        size_t idx = ((size_t)(b * 12 + head) << 16) + (t << 6) + d;
        __hip_bfloat16 hv = __float2bfloat16(v);
        if (which == 0) {
          Qws[idx] = hv;
        } else if (which == 1) {
          Kws[idx] = hv; prekv[idx] = v;
        } else {
          Vws[idx] = hv; prekv[6291456 + idx] = v;
        }
      }
    }
  }
}

// ---------------- proj GEMM: O(8192x768) @ proj_w(768x768)^T + b -> out ----------------
__global__ __launch_bounds__(256) void gemm_proj_kernel(
    const __hip_bfloat16* __restrict__ Ows, const __hip_bfloat16* __restrict__ wproj,
    const float* __restrict__ proj_b, float* __restrict__ out) {
  __shared__ char smem[16384];
  f32x4 acc[4][4];
  const f32x4 z4 = {0.f, 0.f, 0.f, 0.f};
  #pragma unroll
  for (int i = 0; i < 4; ++i)
    #pragma unroll
    for (int j = 0; j < 4; ++j) acc[i][j] = z4;

  const int bn = blockIdx.x, bm = blockIdx.y;
  gemm_tile_compute(Ows, wproj, 768, bm, bn, acc, smem);

  const int lane = threadIdx.x & 63, w = threadIdx.x >> 6;
  const int wr = w >> 1, wc = w & 1;
  const int col0 = lane & 15, g = lane >> 4;
  #pragma unroll
  for (int j = 0; j < 4; ++j) {
    int n = bn * 128 + wc * 64 + j * 16 + col0;
    float bias = proj_b[n];
    #pragma unroll
    for (int i = 0; i < 4; ++i) {
      #pragma unroll
      for (int r = 0; r < 4; ++r) {
        int m = bm * 128 + wr * 64 + i * 16 + g * 4 + r;
        out[(size_t)m * 768 + n] = acc[i][j][r] + bias;
      }
    }
  }
}

// ---------------- flash attention, prefetch-pipelined ----------------
// grid 768: qt = bid/96, bh = bid%96 (qt-blocks of one bh land on one XCD).
// 4 waves x 32 q-rows; K-tiles of 64, K LDS double-buffered, V reg double-buffered.
// Per tile: [issue K/V t+1] vmcnt(4) barrierA | QK^T | V^T write | softmax | P write |
// lgkmcnt(0) barrierB | PV.   48 KB LDS -> 3 blocks/CU.
#define VSWZ(hd) ((((hd) ^ ((hd) >> 3)) & 7) << 4)

__global__ __launch_bounds__(256, 3) void flash_attn(
    const __hip_bfloat16* __restrict__ Qws, const __hip_bfloat16* __restrict__ Kws,
    const __hip_bfloat16* __restrict__ Vws, const __hip_bfloat16* __restrict__ rphb,
    const __hip_bfloat16* __restrict__ rpwb, __hip_bfloat16* __restrict__ Ows) {
  __shared__ alignas(16) char smem[49152];
  char*  s_relh = smem;                         // 8 KB [128][32] bf16 (wave-local stripes)
  char*  s_kt   = smem + 8192;                  // 16 KB: 2 x K tile [64 key][64 hd] swizzled
  char*  s_vt   = smem + 24576;                 // 8 KB V^T [64 hd][64 key] swizzled
  char*  s_pt   = smem + 32768;                 // 16 KB P per-wave stripes (prologue: relw f32)
  float* s_rw   = (float*)(smem + 32768);

  const int tid = threadIdx.x, lane = tid & 63, w = tid >> 6;
  const int g16 = lane >> 4, c16 = lane & 15;
  const int bid = blockIdx.x;
  const int qt = bid / 96, bh = bid - qt * 96;
  const int q0 = qt * 128;
  const int b = bh / 12, head = bh - b * 12;
  const size_t bhbase = (size_t)bh << 16;       // bh*1024*64

  // Q fragments (registers for the whole kernel)
  bf16x8 qf[2][2];
  {
    const __hip_bfloat16* qp = Qws + bhbase + (size_t)(q0 + w * 32 + c16) * 64 + g16 * 8;
    qf[0][0] = *(const bf16x8*)qp;
    qf[0][1] = *(const bf16x8*)(qp + 32);
    qf[1][0] = *(const bf16x8*)(qp + 16 * 64);
    qf[1][1] = *(const bf16x8*)(qp + 16 * 64 + 32);
  }

  const f32x4 z4 = {0.f, 0.f, 0.f, 0.f};

  // --- rel-bias prologue: Gh/Gw = Q(32x64) @ table^T, scatter into wave-local stripes ---
  {
    f32x4 gh[2][4], gw[2][4];
    #pragma unroll
    for (int mb = 0; mb < 2; ++mb)
      #pragma unroll
      for (int nf = 0; nf < 4; ++nf) { gh[mb][nf] = z4; gw[mb][nf] = z4; }
    #pragma unroll
    for (int kc = 0; kc < 2; ++kc) {
      #pragma unroll
      for (int nf = 0; nf < 4; ++nf) {
        int j = nf * 16 + c16;                 // table row (row 63 = zero pad)
        bf16x8 th = *(const bf16x8*)(rphb + j * 64 + kc * 32 + g16 * 8);
        bf16x8 tw = *(const bf16x8*)(rpwb + j * 64 + kc * 32 + g16 * 8);
        gh[0][nf] = __builtin_amdgcn_mfma_f32_16x16x32_bf16(qf[0][kc], th, gh[0][nf], 0, 0, 0);
        gh[1][nf] = __builtin_amdgcn_mfma_f32_16x16x32_bf16(qf[1][kc], th, gh[1][nf], 0, 0, 0);
        gw[0][nf] = __builtin_amdgcn_mfma_f32_16x16x32_bf16(qf[0][kc], tw, gw[0][nf], 0, 0, 0);
        gw[1][nf] = __builtin_amdgcn_mfma_f32_16x16x32_bf16(qf[1][kc], tw, gw[1][nf], 0, 0, 0);
      }
    }
    const int hq = (q0 >> 5) + w;              // h coordinate of this wave's rows
    #pragma unroll
    for (int mb = 0; mb < 2; ++mb) {
      #pragma unroll
      for (int nf = 0; nf < 4; ++nf) {
        int j = nf * 16 + c16;
        int khh = hq - j + 31;
        #pragma unroll
        for (int r = 0; r < 4; ++r) {
          int rowin = mb * 16 + g16 * 4 + r;   // == wq for this row
          int lrow = w * 32 + rowin;
          if (khh >= 0 && khh < 32)
            *(__hip_bfloat16*)(s_relh + (lrow * 32 + khh) * 2) = __float2bfloat16(gh[mb][nf][r]);
          int kww = rowin - j + 31;
          if (kww >= 0 && kww < 32) s_rw[lrow * 32 + kww] = gw[mb][nf][r];
        }
      }
    }
  }
  asm volatile("s_waitcnt lgkmcnt(0)" ::: "memory");
  // rel_w values this thread will ever need (kw = c16 and 16+c16), 16 regs
  float rw0[2][4], rw1[2][4];
  #pragma unroll
  for (int rb = 0; rb < 2; ++rb)
    #pragma unroll
    for (int r = 0; r < 4; ++r) {
      int lrow = w * 32 + rb * 16 + g16 * 4 + r;
      rw0[rb][r] = s_rw[lrow * 32 + c16];
      rw1[rb][r] = s_rw[lrow * 32 + 16 + c16];
    }

  f32x4 o[2][4];
  float m_r[2][4], l_r[2][4];
  #pragma unroll
  for (int rb = 0; rb < 2; ++rb) {
    #pragma unroll
    for (int hf = 0; hf < 4; ++hf) o[rb][hf] = z4;
    #pragma unroll
    for (int r = 0; r < 4; ++r) { m_r[rb][r] = -1e30f; l_r[rb][r] = 0.f; }
  }

  const float SCALE2 = 0.125f * LOG2E;
  const int kp = tid >> 3;            // 0..31 key pair
  const int hd0 = (tid & 7) * 8;      // 0..56

// issue K tile kt into s_kt + bufofs (2 gload_lds, pre-swizzled source)
#define ISSUE_K(kt, bufofs)                                                             \
  {                                                                                     \
    _Pragma("unroll")                                                                   \
    for (int i = 0; i < 2; ++i) {                                                       \
      int c = w * 2 + i;                                                                \
      int row = c * 8 + (lane >> 3);                                                    \
      int cbs = (lane & 7) ^ (row & 7);                                                 \
      const char* g = (const char*)(Kws + bhbase + (size_t)((kt) + row) * 64) + cbs * 16; \
      gload_lds16(g, s_kt + (bufofs) + c * 1024);                                       \
    }                                                                                   \
  }

// issue V tile kt into register pair (2 global_load_dwordx4)
#define ISSUE_V(kt, va, vb)                                                             \
  { const __hip_bfloat16* vr = Vws + bhbase + (size_t)((kt) + 2 * kp) * 64 + hd0;       \
    va = *(const bf16x8*)vr; vb = *(const bf16x8*)(vr + 64); }

// full tile body: QK^T | V^T write | softmax | P write | lgkm+barrierB | PV
#define TILE(kt0v, bufofs, va, vb)                                                      \
  {                                                                                     \
    f32x4 s[2][4];                                                                      \
    _Pragma("unroll")                                                                   \
    for (int rb = 0; rb < 2; ++rb)                                                      \
      _Pragma("unroll")                                                                 \
      for (int kf = 0; kf < 4; ++kf) s[rb][kf] = z4;                                    \
    __builtin_amdgcn_s_setprio(1);                                                      \
    _Pragma("unroll")                                                                   \
    for (int kc = 0; kc < 2; ++kc) {                                                    \
      _Pragma("unroll")                                                                 \
      for (int kf = 0; kf < 4; ++kf) {                                                  \
        int key = kf * 16 + c16;                                                        \
        int byte = (bufofs) + key * 128 + (((kc * 32 + g16 * 8) * 2) ^ ((key & 7) << 4)); \
        bf16x8 kfr = *(const bf16x8*)(s_kt + byte);                                     \
        s[0][kf] = __builtin_amdgcn_mfma_f32_16x16x32_bf16(qf[0][kc], kfr, s[0][kf], 0, 0, 0); \
        s[1][kf] = __builtin_amdgcn_mfma_f32_16x16x32_bf16(qf[1][kc], kfr, s[1][kf], 0, 0, 0); \
      }                                                                                 \
    }                                                                                   \
    __builtin_amdgcn_s_setprio(0);                                                      \
    _Pragma("unroll")                                                                   \
    for (int j = 0; j < 8; ++j) {                                                       \
      int hd = hd0 + j;                                                                 \
      union { ushort2 u2; uint32_t u; } pk;                                             \
      pk.u2.x = (unsigned short)va[j];                                                  \
      pk.u2.y = (unsigned short)vb[j];                                                  \
      *(uint32_t*)(s_vt + hd * 128 + ((4 * kp) ^ VSWZ(hd))) = pk.u;                     \
    }                                                                                   \
    int kh0 = (kt0v) >> 5;                                                              \
    f32x4 facv[2];                                                                      \
    _Pragma("unroll")                                                                   \
    for (int rb = 0; rb < 2; ++rb) {                                                    \
      float rh0[4], rh1[4];                                                             \
      _Pragma("unroll")                                                                 \
      for (int r = 0; r < 4; ++r) {                                                     \
        int lrow = w * 32 + rb * 16 + g16 * 4 + r;                                      \
        uint32_t rhu = *(const uint32_t*)(s_relh + (lrow * 32 + kh0) * 2);              \
        rh0[r] = bf16bits_to_f32((unsigned short)(rhu & 0xffff));                       \
        rh1[r] = bf16bits_to_f32((unsigned short)(rhu >> 16));                          \
      }                                                                                 \
      _Pragma("unroll")                                                                 \
      for (int kf = 0; kf < 4; ++kf)                                                    \
        _Pragma("unroll")                                                               \
        for (int r = 0; r < 4; ++r)                                                     \
          s[rb][kf][r] = fmaf(s[rb][kf][r], SCALE2,                                     \
                              ((kf >> 1) ? rh1[r] : rh0[r]) +                           \
                              ((kf & 1) ? rw1[rb][r] : rw0[rb][r]));                    \
      _Pragma("unroll")                                                                 \
      for (int r = 0; r < 4; ++r) {                                                     \
        float tm = fmaxf(fmaxf(s[rb][0][r], s[rb][1][r]), fmaxf(s[rb][2][r], s[rb][3][r])); \
        tm = fmaxf(tm, __shfl_xor(tm, 1));                                              \
        tm = fmaxf(tm, __shfl_xor(tm, 2));                                              \
        tm = fmaxf(tm, __shfl_xor(tm, 4));                                              \
        tm = fmaxf(tm, __shfl_xor(tm, 8));                                              \
        float mold = m_r[rb][r];                                                        \
        float mnew = fmaxf(mold, tm);                                                   \
        float fac = exp2_fast(mold - mnew);                                             \
        m_r[rb][r] = mnew;                                                              \
        facv[rb][r] = fac;                                                              \
        float psum = 0.f;                                                               \
        _Pragma("unroll")                                                               \
        for (int kf = 0; kf < 4; ++kf) {                                                \
          float p = exp2_fast(s[rb][kf][r] - mnew);                                     \
          s[rb][kf][r] = p;                                                             \
          psum += p;                                                                    \
        }                                                                               \
        psum += __shfl_xor(psum, 1);                                                    \
        psum += __shfl_xor(psum, 2);                                                    \
        psum += __shfl_xor(psum, 4);                                                    \
        psum += __shfl_xor(psum, 8);                                                    \
        l_r[rb][r] = fmaf(l_r[rb][r], fac, psum);                                       \
      }                                                                                 \
    }                                                                                   \
    bool nr = (facv[0][0] == 1.f) & (facv[0][1] == 1.f) & (facv[0][2] == 1.f) &         \
              (facv[0][3] == 1.f) & (facv[1][0] == 1.f) & (facv[1][1] == 1.f) &         \
              (facv[1][2] == 1.f) & (facv[1][3] == 1.f);                                \
    if (!__all(nr)) {                                                                   \
      _Pragma("unroll")                                                                 \
      for (int rb = 0; rb < 2; ++rb)                                                    \
        _Pragma("unroll")                                                               \
        for (int hf = 0; hf < 4; ++hf) o[rb][hf] *= facv[rb];                           \
    }                                                                                   \
    _Pragma("unroll")                                                                   \
    for (int rb = 0; rb < 2; ++rb)                                                      \
      _Pragma("unroll")                                                                 \
      for (int kf = 0; kf < 4; ++kf) {                                                  \
        int key = kf * 16 + c16;                                                        \
        _Pragma("unroll")                                                               \
        for (int r = 0; r < 4; ++r) {                                                   \
          int prow = rb * 16 + g16 * 4 + r;                                             \
          int byte = w * 4096 + prow * 128 + ((key * 2) ^ ((prow & 7) << 4));           \
          *(__hip_bfloat16*)(s_pt + byte) = __float2bfloat16(s[rb][kf][r]);             \
        }                                                                               \
      }                                                                                 \
    asm volatile("s_waitcnt lgkmcnt(0)" ::: "memory");                                  \
    __builtin_amdgcn_s_barrier();                                                       \
    __builtin_amdgcn_s_setprio(1);                                                      \
    _Pragma("unroll")                                                                   \
    for (int kc = 0; kc < 2; ++kc) {                                                    \
      bf16x8 pf[2];                                                                     \
      _Pragma("unroll")                                                                 \
      for (int rb = 0; rb < 2; ++rb) {                                                  \
        int prow = rb * 16 + c16;                                                       \
        int byte = w * 4096 + prow * 128 + (((kc * 32 + g16 * 8) * 2) ^ ((prow & 7) << 4)); \
        pf[rb] = *(const bf16x8*)(s_pt + byte);                                         \
      }                                                                                 \
      _Pragma("unroll")                                                                 \
      for (int hf = 0; hf < 4; ++hf) {                                                  \
        int hd = hf * 16 + c16;                                                         \
        int byte = hd * 128 + (((kc * 32 + g16 * 8) * 2) ^ VSWZ(hd));                   \
        bf16x8 vf = *(const bf16x8*)(s_vt + byte);                                      \
        o[0][hf] = __builtin_amdgcn_mfma_f32_16x16x32_bf16(pf[0], vf, o[0][hf], 0, 0, 0); \
        o[1][hf] = __builtin_amdgcn_mfma_f32_16x16x32_bf16(pf[1], vf, o[1][hf], 0, 0, 0); \
      }                                                                                 \
    }                                                                                   \
    __builtin_amdgcn_s_setprio(0);                                                      \
  }

  bf16x8 vaA, vbA, vaB, vbB;
  // prologue: prefetch tile 0 into buf0 / regs A
  ISSUE_K(0, 0);
  ISSUE_V(0, vaA, vbA);

  for (int it = 0; it < 8; ++it) {
    int t0 = it * 128;
    // tile t0 (buf0, regs A); prefetch t0+64 into buf1 / regs B
    ISSUE_K((t0 + 64) & 1023, 8192);
    ISSUE_V((t0 + 64) & 1023, vaB, vbB);
    asm volatile("s_waitcnt vmcnt(4)" ::: "memory");
    __builtin_amdgcn_s_barrier();
    TILE(t0, 0, vaA, vbA);
    // tile t0+64 (buf1, regs B); prefetch t0+128 (wraps) into buf0 / regs A
    ISSUE_K((t0 + 128) & 1023, 0);
    ISSUE_V((t0 + 128) & 1023, vaA, vbA);
    asm volatile("s_waitcnt vmcnt(4)" ::: "memory");
    __builtin_amdgcn_s_barrier();
    TILE(t0 + 64, 8192, vaB, vbB);
  }
  asm volatile("s_waitcnt vmcnt(0)" ::: "memory");

  // --- epilogue: normalize + write O in (B,N,C) layout ---
  #pragma unroll
  for (int rb = 0; rb < 2; ++rb) {
    #pragma unroll
    for (int r = 0; r < 4; ++r) {
      int row = q0 + w * 32 + rb * 16 + g16 * 4 + r;
      float inv = 1.0f / l_r[rb][r];
      size_t base = ((size_t)b * 1024 + row) * 768 + head * 64;
      #pragma unroll
      for (int hf = 0; hf < 4; ++hf)
        Ows[base + hf * 16 + c16] = __float2bfloat16(o[rb][hf][r] * inv);
    }
  }
#undef ISSUE_K
#undef ISSUE_V
#undef TILE
}

// ---------------- launch ----------------
extern "C" void kernel_launch(void* const* d_in, const int* in_sizes, int n_in,
                              void* d_out, int out_size, void* d_ws, size_t ws_size,
                              hipStream_t stream) {
  const float* x      = (const float*)d_in[0];
  const float* qkv_w  = (const float*)d_in[1];
  const float* qkv_b  = (const float*)d_in[2];
  const float* proj_w = (const float*)d_in[3];
  const float* proj_b = (const float*)d_in[4];
  const float* rph    = (const float*)d_in[5];
  const float* rpw    = (const float*)d_in[6];

  char* ws = (char*)d_ws;
  __hip_bfloat16* xb    = (__hip_bfloat16*)(ws);              // 12582912 B (reused as Ows)
  __hip_bfloat16* wqkv  = (__hip_bfloat16*)(ws + 12582912);   // 3538944 B
  __hip_bfloat16* wproj = (__hip_bfloat16*)(ws + 16121856);   // 1179648 B
  __hip_bfloat16* Qws   = (__hip_bfloat16*)(ws + 17301504);   // 12582912 B
  __hip_bfloat16* Kws   = (__hip_bfloat16*)(ws + 29884416);   // 12582912 B
  __hip_bfloat16* Vws   = (__hip_bfloat16*)(ws + 42467328);   // 12582912 B
  __hip_bfloat16* rphb  = (__hip_bfloat16*)(ws + 55050240);   // 8192 B (64x64, row 63 = 0)
  __hip_bfloat16* rpwb  = (__hip_bfloat16*)(ws + 55058432);   // 8192 B
  __hip_bfloat16* Ows   = xb;                                  // reuse after qkv GEMM

  float* out   = (float*)d_out;
  float* prekv = out + 6291456;

  cvt_bf16<<<6144, 256, 0, stream>>>(x, xb, 1572864);
  cvt_bf16<<<1728, 256, 0, stream>>>(qkv_w, wqkv, 442368);
  cvt_bf16<<<576, 256, 0, stream>>>(proj_w, wproj, 147456);
  cvt_bf16_pad<<<4, 256, 0, stream>>>(rph, rphb, 1008, 1024, LOG2E);
  cvt_bf16_pad<<<4, 256, 0, stream>>>(rpw, rpwb, 1008, 1024, LOG2E);
  gemm_qkv_kernel<<<dim3(18, 64), 256, 0, stream>>>(xb, wqkv, qkv_b, Qws, Kws, Vws, prekv);
  flash_attn<<<768, 256, 0, stream>>>(Qws, Kws, Vws, rphb, rpwb, Ows);
  gemm_proj_kernel<<<dim3(6, 64), 256, 0, stream>>>(Ows, wproj, proj_b, out);
}

// Round 8
// 345.447 us; speedup vs baseline: 1.3720x; 1.3720x over previous
//
#include <hip/hip_runtime.h>
#include <hip/hip_bf16.h>
#include <stdint.h>

typedef __attribute__((ext_vector_type(8))) short bf16x8;   // 8 bf16 = 4 VGPRs
typedef __attribute__((ext_vector_type(4))) float f32x4;

#define LOG2E 1.4426950408889634f

__device__ __forceinline__ float exp2_fast(float x) {
  float r; asm("v_exp_f32 %0, %1" : "=v"(r) : "v"(x)); return r;
}

__device__ __forceinline__ float bf16bits_to_f32(unsigned short h) {
  union { uint32_t u; float f; } c;
  c.u = ((uint32_t)h) << 16;
  return c.f;
}

// ---------------- async global -> LDS (16B per lane) ----------------
__device__ __forceinline__ void gload_lds16(const void* g, void* l) {
  typedef __attribute__((address_space(1))) void gv_t;
  typedef __attribute__((address_space(3))) void lv_t;
  __builtin_amdgcn_global_load_lds((gv_t*)(uintptr_t)g,
                                   (lv_t*)(uint32_t)(uintptr_t)l, 16, 0, 0);
}

// ---------------- fp32 -> bf16 cast ----------------
__global__ __launch_bounds__(256) void cvt_bf16(const float* __restrict__ src,
                                                __hip_bfloat16* __restrict__ dst, int n4) {
  int i = blockIdx.x * 256 + threadIdx.x;
  if (i < n4) {
    float4 f = ((const float4*)src)[i];
    union { ushort4 u; __hip_bfloat16 h[4]; } pk;
    pk.h[0] = __float2bfloat16(f.x);
    pk.h[1] = __float2bfloat16(f.y);
    pk.h[2] = __float2bfloat16(f.z);
    pk.h[3] = __float2bfloat16(f.w);
    ((ushort4*)dst)[i] = pk.u;
  }
}

// fp32 -> bf16 with scale + zero-padding beyond n4src (63-row rel tables -> 64 rows)
__global__ __launch_bounds__(256) void cvt_bf16_pad(const float* __restrict__ src,
                                                    __hip_bfloat16* __restrict__ dst,
                                                    int n4src, int n4tot, float scale) {
  int i = blockIdx.x * 256 + threadIdx.x;
  if (i < n4tot) {
    float4 f = (i < n4src) ? ((const float4*)src)[i] : make_float4(0.f, 0.f, 0.f, 0.f);
    union { ushort4 u; __hip_bfloat16 h[4]; } pk;
    pk.h[0] = __float2bfloat16(f.x * scale);
    pk.h[1] = __float2bfloat16(f.y * scale);
    pk.h[2] = __float2bfloat16(f.z * scale);
    pk.h[3] = __float2bfloat16(f.w * scale);
    ((ushort4*)dst)[i] = pk.u;
  }
}

// ---------------- shared 128x128 bf16 GEMM body (A[M][K] @ B[N][K]^T) ----------------
__device__ __forceinline__ void gemm_tile_compute(const __hip_bfloat16* __restrict__ A,
                                                  const __hip_bfloat16* __restrict__ Bm,
                                                  int K, int bm, int bn,
                                                  f32x4 acc[4][4], char* lbase) {
  const int tid = threadIdx.x;
  const int lane = tid & 63, w = tid >> 6;
  const int wr = w >> 1, wc = w & 1;
  const int rrow = lane & 15, g16 = lane >> 4;

  for (int k0 = 0; k0 < K; k0 += 32) {
    #pragma unroll
    for (int i = 0; i < 2; ++i) {
      int c = i * 4 + w;
      int b = c * 1024 + (lane << 4);
      int row = b >> 6;           // 64B rows
      int cbs = ((b >> 4) & 3) ^ (row & 3);
      const char* ga = (const char*)(A + (size_t)(bm * 128 + row) * K + k0) + cbs * 16;
      gload_lds16(ga, lbase + c * 1024);
      const char* gb = (const char*)(Bm + (size_t)(bn * 128 + row) * K + k0) + cbs * 16;
      gload_lds16(gb, lbase + 8192 + c * 1024);
    }
    asm volatile("s_waitcnt vmcnt(0)" ::: "memory");
    __syncthreads();

    bf16x8 af[4], bfr[4];
    #pragma unroll
    for (int i = 0; i < 4; ++i) {
      int row = wr * 64 + i * 16 + rrow;
      af[i] = *(const bf16x8*)(lbase + row * 64 + ((g16 * 16) ^ ((row & 3) << 4)));
      int col = wc * 64 + i * 16 + rrow;
      bfr[i] = *(const bf16x8*)(lbase + 8192 + col * 64 + ((g16 * 16) ^ ((col & 3) << 4)));
    }
    __builtin_amdgcn_s_setprio(1);
    #pragma unroll
    for (int i = 0; i < 4; ++i)
      #pragma unroll
      for (int j = 0; j < 4; ++j)
        acc[i][j] = __builtin_amdgcn_mfma_f32_16x16x32_bf16(af[i], bfr[j], acc[i][j], 0, 0, 0);
    __builtin_amdgcn_s_setprio(0);
    __syncthreads();
  }
}

// ---------------- qkv GEMM: x(8192x768) @ qkv_w(2304x768)^T + b -> packed Q/K/V + prekv ----
__global__ __launch_bounds__(256) void gemm_qkv_kernel(
    const __hip_bfloat16* __restrict__ xb, const __hip_bfloat16* __restrict__ wqkv,
    const float* __restrict__ qkv_b,
    __hip_bfloat16* __restrict__ Qws, __hip_bfloat16* __restrict__ Kws,
    __hip_bfloat16* __restrict__ Vws, float* __restrict__ prekv) {
  __shared__ char smem[16384];
  f32x4 acc[4][4];
  const f32x4 z4 = {0.f, 0.f, 0.f, 0.f};
  #pragma unroll
  for (int i = 0; i < 4; ++i)
    #pragma unroll
    for (int j = 0; j < 4; ++j) acc[i][j] = z4;

  const int bn = blockIdx.x, bm = blockIdx.y;
  gemm_tile_compute(xb, wqkv, 768, bm, bn, acc, smem);

  const int lane = threadIdx.x & 63, w = threadIdx.x >> 6;
  const int wr = w >> 1, wc = w & 1;
  const int col0 = lane & 15, g = lane >> 4;
  #pragma unroll
  for (int j = 0; j < 4; ++j) {
    int n = bn * 128 + wc * 64 + j * 16 + col0;
    float bias = qkv_b[n];
    int which = n / 768;
    int head = (n >> 6) % 12;
    int d = n & 63;
    #pragma unroll
    for (int i = 0; i < 4; ++i) {
      #pragma unroll
      for (int r = 0; r < 4; ++r) {
        int m = bm * 128 + wr * 64 + i * 16 + g * 4 + r;
        float v = acc[i][j][r] + bias;
        int b = m >> 10, t = m & 1023;
        size_t idx = ((size_t)(b * 12 + head) << 16) + (t << 6) + d;
        __hip_bfloat16 hv = __float2bfloat16(v);
        if (which == 0) {
          Qws[idx] = hv;
        } else if (which == 1) {
          Kws[idx] = hv; prekv[idx] = v;
        } else {
          Vws[idx] = hv; prekv[6291456 + idx] = v;
        }
      }
    }
  }
}

// ---------------- proj GEMM: O(8192x768) @ proj_w(768x768)^T + b -> out ----------------
__global__ __launch_bounds__(256) void gemm_proj_kernel(
    const __hip_bfloat16* __restrict__ Ows, const __hip_bfloat16* __restrict__ wproj,
    const float* __restrict__ proj_b, float* __restrict__ out) {
  __shared__ char smem[16384];
  f32x4 acc[4][4];
  const f32x4 z4 = {0.f, 0.f, 0.f, 0.f};
  #pragma unroll
  for (int i = 0; i < 4; ++i)
    #pragma unroll
    for (int j = 0; j < 4; ++j) acc[i][j] = z4;

  const int bn = blockIdx.x, bm = blockIdx.y;
  gemm_tile_compute(Ows, wproj, 768, bm, bn, acc, smem);

  const int lane = threadIdx.x & 63, w = threadIdx.x >> 6;
  const int wr = w >> 1, wc = w & 1;
  const int col0 = lane & 15, g = lane >> 4;
  #pragma unroll
  for (int j = 0; j < 4; ++j) {
    int n = bn * 128 + wc * 64 + j * 16 + col0;
    float bias = proj_b[n];
    #pragma unroll
    for (int i = 0; i < 4; ++i) {
      #pragma unroll
      for (int r = 0; r < 4; ++r) {
        int m = bm * 128 + wr * 64 + i * 16 + g * 4 + r;
        out[(size_t)m * 768 + n] = acc[i][j][r] + bias;
      }
    }
  }
}

// ---------------- flash attention, K-prefetch pipelined ----------------
// grid 768: qt = bid/96, bh = bid%96. 4 waves x 32 q-rows; K-tiles of 64.
// K LDS double-buffered, prefetched ONE FULL TILE ahead (2 gload_lds stay in flight
// across both barriers); V loaded in-tile, latency covered by QK^T.
// Per tile: V(t) loads | K(t+1) issue | vmcnt(4) barA | QK^T(buf) | vmcnt(2) |
// V^T write | softmax | P write | lgkm barB | PV.
// No launch_bounds min-occupancy clause: R4-R7's (256,3) forced 84 VGPR -> scratch spill
// (WRITE_SIZE 42-275 MB). 48 KB LDS -> 3 blocks/CU when VGPR <= 170.
#define VSWZ(hd) ((((hd) ^ ((hd) >> 3)) & 7) << 4)

__global__ __launch_bounds__(256) void flash_attn(
    const __hip_bfloat16* __restrict__ Qws, const __hip_bfloat16* __restrict__ Kws,
    const __hip_bfloat16* __restrict__ Vws, const __hip_bfloat16* __restrict__ rphb,
    const __hip_bfloat16* __restrict__ rpwb, __hip_bfloat16* __restrict__ Ows) {
  __shared__ alignas(16) char smem[49152];
  char*  s_relh = smem;                         // 8 KB [128][32] bf16 (wave-local stripes)
  char*  s_kt   = smem + 8192;                  // 16 KB: 2 x K tile [64 key][64 hd] swizzled
  char*  s_vt   = smem + 24576;                 // 8 KB V^T [64 hd][64 key] swizzled
  char*  s_pt   = smem + 32768;                 // 16 KB P per-wave stripes (prologue: relw f32)
  float* s_rw   = (float*)(smem + 32768);

  const int tid = threadIdx.x, lane = tid & 63, w = tid >> 6;
  const int g16 = lane >> 4, c16 = lane & 15;
  const int bid = blockIdx.x;
  const int qt = bid / 96, bh = bid - qt * 96;
  const int q0 = qt * 128;
  const int b = bh / 12, head = bh - b * 12;
  const size_t bhbase = (size_t)bh << 16;       // bh*1024*64

  // Q fragments (registers for the whole kernel)
  bf16x8 qf[2][2];
  {
    const __hip_bfloat16* qp = Qws + bhbase + (size_t)(q0 + w * 32 + c16) * 64 + g16 * 8;
    qf[0][0] = *(const bf16x8*)qp;
    qf[0][1] = *(const bf16x8*)(qp + 32);
    qf[1][0] = *(const bf16x8*)(qp + 16 * 64);
    qf[1][1] = *(const bf16x8*)(qp + 16 * 64 + 32);
  }

  const f32x4 z4 = {0.f, 0.f, 0.f, 0.f};

  // --- rel-bias prologue: Gh/Gw = Q(32x64) @ table^T, scatter into wave-local stripes ---
  {
    f32x4 gh[2][4], gw[2][4];
    #pragma unroll
    for (int mb = 0; mb < 2; ++mb)
      #pragma unroll
      for (int nf = 0; nf < 4; ++nf) { gh[mb][nf] = z4; gw[mb][nf] = z4; }
    #pragma unroll
    for (int kc = 0; kc < 2; ++kc) {
      #pragma unroll
      for (int nf = 0; nf < 4; ++nf) {
        int j = nf * 16 + c16;                 // table row (row 63 = zero pad)
        bf16x8 th = *(const bf16x8*)(rphb + j * 64 + kc * 32 + g16 * 8);
        bf16x8 tw = *(const bf16x8*)(rpwb + j * 64 + kc * 32 + g16 * 8);
        gh[0][nf] = __builtin_amdgcn_mfma_f32_16x16x32_bf16(qf[0][kc], th, gh[0][nf], 0, 0, 0);
        gh[1][nf] = __builtin_amdgcn_mfma_f32_16x16x32_bf16(qf[1][kc], th, gh[1][nf], 0, 0, 0);
        gw[0][nf] = __builtin_amdgcn_mfma_f32_16x16x32_bf16(qf[0][kc], tw, gw[0][nf], 0, 0, 0);
        gw[1][nf] = __builtin_amdgcn_mfma_f32_16x16x32_bf16(qf[1][kc], tw, gw[1][nf], 0, 0, 0);
      }
    }
    const int hq = (q0 >> 5) + w;              // h coordinate of this wave's rows
    #pragma unroll
    for (int mb = 0; mb < 2; ++mb) {
      #pragma unroll
      for (int nf = 0; nf < 4; ++nf) {
        int j = nf * 16 + c16;
        int khh = hq - j + 31;
        #pragma unroll
        for (int r = 0; r < 4; ++r) {
          int rowin = mb * 16 + g16 * 4 + r;   // == wq for this row
          int lrow = w * 32 + rowin;
          if (khh >= 0 && khh < 32)
            *(__hip_bfloat16*)(s_relh + (lrow * 32 + khh) * 2) = __float2bfloat16(gh[mb][nf][r]);
          int kww = rowin - j + 31;
          if (kww >= 0 && kww < 32) s_rw[lrow * 32 + kww] = gw[mb][nf][r];
        }
      }
    }
  }
  asm volatile("s_waitcnt lgkmcnt(0)" ::: "memory");
  // rel_w values this thread will ever need (kw = c16 and 16+c16), 16 regs
  float rw0[2][4], rw1[2][4];
  #pragma unroll
  for (int rb = 0; rb < 2; ++rb)
    #pragma unroll
    for (int r = 0; r < 4; ++r) {
      int lrow = w * 32 + rb * 16 + g16 * 4 + r;
      rw0[rb][r] = s_rw[lrow * 32 + c16];
      rw1[rb][r] = s_rw[lrow * 32 + 16 + c16];
    }

  f32x4 o[2][4];
  float m_r[2][4], l_r[2][4];
  #pragma unroll
  for (int rb = 0; rb < 2; ++rb) {
    #pragma unroll
    for (int hf = 0; hf < 4; ++hf) o[rb][hf] = z4;
    #pragma unroll
    for (int r = 0; r < 4; ++r) { m_r[rb][r] = -1e30f; l_r[rb][r] = 0.f; }
  }

  const float SCALE2 = 0.125f * LOG2E;
  const int kp = tid >> 3;            // 0..31 key pair
  const int hd0 = (tid & 7) * 8;      // 0..56
  const int krow = (w * 2) * 8 + (lane >> 3);       // rows for chunk c0 = w*2
  const int krow2 = (w * 2 + 1) * 8 + (lane >> 3);  // rows for chunk c0+1
  const int kcbs = ((lane & 7) ^ (krow & 7)) * 16;
  const int kcbs2 = ((lane & 7) ^ (krow2 & 7)) * 16;

  // prologue: prefetch K tile 0 into buf0
  gload_lds16((const char*)(Kws + bhbase + (size_t)krow * 64) + kcbs,
              s_kt + (w * 2) * 1024);
  gload_lds16((const char*)(Kws + bhbase + (size_t)krow2 * 64) + kcbs2,
              s_kt + (w * 2 + 1) * 1024);

  for (int t = 0; t < 16; ++t) {
    const int kt0 = t << 6;
    const int bo = (t & 1) << 13;          // current K buffer
    const int bn = ((t + 1) & 1) << 13;    // next K buffer
    // (1) V(t) register loads (oldest after K(t))
    const __hip_bfloat16* vr = Vws + bhbase + (size_t)(kt0 + 2 * kp) * 64 + hd0;
    bf16x8 va = *(const bf16x8*)vr;
    bf16x8 vb = *(const bf16x8*)(vr + 64);
    asm volatile("" ::: "memory");         // pin V-before-K(t+1) issue order
    // (2) K(t+1) prefetch into the other buffer
    {
      const int ktn = (kt0 + 64) & 1023;
      gload_lds16((const char*)(Kws + bhbase + (size_t)(ktn + krow) * 64) + kcbs,
                  s_kt + bn + (w * 2) * 1024);
      gload_lds16((const char*)(Kws + bhbase + (size_t)(ktn + krow2) * 64) + kcbs2,
                  s_kt + bn + (w * 2 + 1) * 1024);
    }
    // (3) drain K(t) only; V(t) + K(t+1) stay in flight
    asm volatile("s_waitcnt vmcnt(4)" ::: "memory");
    __builtin_amdgcn_s_barrier();

    // (4) S = Q K^T from s_kt+bo
    f32x4 s[2][4];
    #pragma unroll
    for (int rb = 0; rb < 2; ++rb)
      #pragma unroll
      for (int kf = 0; kf < 4; ++kf) s[rb][kf] = z4;
    __builtin_amdgcn_s_setprio(1);
    #pragma unroll
    for (int kc = 0; kc < 2; ++kc) {
      #pragma unroll
      for (int kf = 0; kf < 4; ++kf) {
        int key = kf * 16 + c16;
        int byte = bo + key * 128 + (((kc * 32 + g16 * 8) * 2) ^ ((key & 7) << 4));
        bf16x8 kfr = *(const bf16x8*)(s_kt + byte);
        s[0][kf] = __builtin_amdgcn_mfma_f32_16x16x32_bf16(qf[0][kc], kfr, s[0][kf], 0, 0, 0);
        s[1][kf] = __builtin_amdgcn_mfma_f32_16x16x32_bf16(qf[1][kc], kfr, s[1][kf], 0, 0, 0);
      }
    }
    __builtin_amdgcn_s_setprio(0);

    // (5) V(t) arrived (covered by QK^T); write V^T (paired keys, 2-way banks)
    asm volatile("s_waitcnt vmcnt(2)" ::: "memory");
    #pragma unroll
    for (int j = 0; j < 8; ++j) {
      int hd = hd0 + j;
      union { ushort2 u2; uint32_t u; } pk;
      pk.u2.x = (unsigned short)va[j];
      pk.u2.y = (unsigned short)vb[j];
      *(uint32_t*)(s_vt + hd * 128 + ((4 * kp) ^ VSWZ(hd))) = pk.u;
    }

    // (6) bias + online softmax (log2 domain, bf16 relh)
    int kh0 = kt0 >> 5;
    f32x4 facv[2];
    #pragma unroll
    for (int rb = 0; rb < 2; ++rb) {
      float rh0[4], rh1[4];
      #pragma unroll
      for (int r = 0; r < 4; ++r) {
        int lrow = w * 32 + rb * 16 + g16 * 4 + r;
        uint32_t rhu = *(const uint32_t*)(s_relh + (lrow * 32 + kh0) * 2);
        rh0[r] = bf16bits_to_f32((unsigned short)(rhu & 0xffff));
        rh1[r] = bf16bits_to_f32((unsigned short)(rhu >> 16));
      }
      #pragma unroll
      for (int kf = 0; kf < 4; ++kf)
        #pragma unroll
        for (int r = 0; r < 4; ++r)
          s[rb][kf][r] = fmaf(s[rb][kf][r], SCALE2,
                              ((kf >> 1) ? rh1[r] : rh0[r]) +
                              ((kf & 1) ? rw1[rb][r] : rw0[rb][r]));
      #pragma unroll
      for (int r = 0; r < 4; ++r) {
        float tm = fmaxf(fmaxf(s[rb][0][r], s[rb][1][r]), fmaxf(s[rb][2][r], s[rb][3][r]));
        tm = fmaxf(tm, __shfl_xor(tm, 1));
        tm = fmaxf(tm, __shfl_xor(tm, 2));
        tm = fmaxf(tm, __shfl_xor(tm, 4));
        tm = fmaxf(tm, __shfl_xor(tm, 8));
        float mold = m_r[rb][r];
        float mnew = fmaxf(mold, tm);
        float fac = exp2_fast(mold - mnew);
        m_r[rb][r] = mnew;
        facv[rb][r] = fac;
        float psum = 0.f;
        #pragma unroll
        for (int kf = 0; kf < 4; ++kf) {
          float p = exp2_fast(s[rb][kf][r] - mnew);
          s[rb][kf][r] = p;
          psum += p;
        }
        psum += __shfl_xor(psum, 1);
        psum += __shfl_xor(psum, 2);
        psum += __shfl_xor(psum, 4);
        psum += __shfl_xor(psum, 8);
        l_r[rb][r] = fmaf(l_r[rb][r], fac, psum);
      }
    }
    bool nr = (facv[0][0] == 1.f) & (facv[0][1] == 1.f) & (facv[0][2] == 1.f) &
              (facv[0][3] == 1.f) & (facv[1][0] == 1.f) & (facv[1][1] == 1.f) &
              (facv[1][2] == 1.f) & (facv[1][3] == 1.f);
    if (!__all(nr)) {
      #pragma unroll
      for (int rb = 0; rb < 2; ++rb)
        #pragma unroll
        for (int hf = 0; hf < 4; ++hf) o[rb][hf] *= facv[rb];   // component-wise (per row)
    }

    // (7) P -> wave-local LDS stripe
    #pragma unroll
    for (int rb = 0; rb < 2; ++rb)
      #pragma unroll
      for (int kf = 0; kf < 4; ++kf) {
        int key = kf * 16 + c16;
        #pragma unroll
        for (int r = 0; r < 4; ++r) {
          int prow = rb * 16 + g16 * 4 + r;
          int byte = w * 4096 + prow * 128 + ((key * 2) ^ ((prow & 7) << 4));
          *(__hip_bfloat16*)(s_pt + byte) = __float2bfloat16(s[rb][kf][r]);
        }
      }

    // (8) V^T/P writes visible to all waves
    asm volatile("s_waitcnt lgkmcnt(0)" ::: "memory");
    __builtin_amdgcn_s_barrier();

    // (9) O += P V
    __builtin_amdgcn_s_setprio(1);
    #pragma unroll
    for (int kc = 0; kc < 2; ++kc) {
      bf16x8 pf[2];
      #pragma unroll
      for (int rb = 0; rb < 2; ++rb) {
        int prow = rb * 16 + c16;
        int byte = w * 4096 + prow * 128 + (((kc * 32 + g16 * 8) * 2) ^ ((prow & 7) << 4));
        pf[rb] = *(const bf16x8*)(s_pt + byte);
      }
      #pragma unroll
      for (int hf = 0; hf < 4; ++hf) {
        int hd = hf * 16 + c16;
        int byte = hd * 128 + (((kc * 32 + g16 * 8) * 2) ^ VSWZ(hd));
        bf16x8 vf = *(const bf16x8*)(s_vt + byte);
        o[0][hf] = __builtin_amdgcn_mfma_f32_16x16x32_bf16(pf[0], vf, o[0][hf], 0, 0, 0);
        o[1][hf] = __builtin_amdgcn_mfma_f32_16x16x32_bf16(pf[1], vf, o[1][hf], 0, 0, 0);
      }
    }
    __builtin_amdgcn_s_setprio(0);
  }
  asm volatile("s_waitcnt vmcnt(0)" ::: "memory");   // drain last (wrapped) prefetch

  // --- epilogue: normalize + write O in (B,N,C) layout ---
  #pragma unroll
  for (int rb = 0; rb < 2; ++rb) {
    #pragma unroll
    for (int r = 0; r < 4; ++r) {
      int row = q0 + w * 32 + rb * 16 + g16 * 4 + r;
      float inv = 1.0f / l_r[rb][r];
      size_t base = ((size_t)b * 1024 + row) * 768 + head * 64;
      #pragma unroll
      for (int hf = 0; hf < 4; ++hf)
        Ows[base + hf * 16 + c16] = __float2bfloat16(o[rb][hf][r] * inv);
    }
  }
}

// ---------------- launch ----------------
extern "C" void kernel_launch(void* const* d_in, const int* in_sizes, int n_in,
                              void* d_out, int out_size, void* d_ws, size_t ws_size,
                              hipStream_t stream) {
  const float* x      = (const float*)d_in[0];
  const float* qkv_w  = (const float*)d_in[1];
  const float* qkv_b  = (const float*)d_in[2];
  const float* proj_w = (const float*)d_in[3];
  const float* proj_b = (const float*)d_in[4];
  const float* rph    = (const float*)d_in[5];
  const float* rpw    = (const float*)d_in[6];

  char* ws = (char*)d_ws;
  __hip_bfloat16* xb    = (__hip_bfloat16*)(ws);              // 12582912 B (reused as Ows)
  __hip_bfloat16* wqkv  = (__hip_bfloat16*)(ws + 12582912);   // 3538944 B
  __hip_bfloat16* wproj = (__hip_bfloat16*)(ws + 16121856);   // 1179648 B
  __hip_bfloat16* Qws   = (__hip_bfloat16*)(ws + 17301504);   // 12582912 B
  __hip_bfloat16* Kws   = (__hip_bfloat16*)(ws + 29884416);   // 12582912 B
  __hip_bfloat16* Vws   = (__hip_bfloat16*)(ws + 42467328);   // 12582912 B
  __hip_bfloat16* rphb  = (__hip_bfloat16*)(ws + 55050240);   // 8192 B (64x64, row 63 = 0)
  __hip_bfloat16* rpwb  = (__hip_bfloat16*)(ws + 55058432);   // 8192 B
  __hip_bfloat16* Ows   = xb;                                  // reuse after qkv GEMM

  float* out   = (float*)d_out;
  float* prekv = out + 6291456;

  cvt_bf16<<<6144, 256, 0, stream>>>(x, xb, 1572864);
  cvt_bf16<<<1728, 256, 0, stream>>>(qkv_w, wqkv, 442368);
  cvt_bf16<<<576, 256, 0, stream>>>(proj_w, wproj, 147456);
  cvt_bf16_pad<<<4, 256, 0, stream>>>(rph, rphb, 1008, 1024, LOG2E);
  cvt_bf16_pad<<<4, 256, 0, stream>>>(rpw, rpwb, 1008, 1024, LOG2E);
  gemm_qkv_kernel<<<dim3(18, 64), 256, 0, stream>>>(xb, wqkv, qkv_b, Qws, Kws, Vws, prekv);
  flash_attn<<<768, 256, 0, stream>>>(Qws, Kws, Vws, rphb, rpwb, Ows);
  gemm_proj_kernel<<<dim3(6, 64), 256, 0, stream>>>(Ows, wproj, proj_b, out);
}